// Round 8
// baseline (565.448 us; speedup 1.0000x reference)
//
#include <hip/hip_runtime.h>
#include <math.h>

#define MM 1024      // checks
#define NN 2048      // vars
#define BB 128       // batch
#define TT 5         // iterations
#define EE 6144      // edges

typedef __bf16 bf16x8 __attribute__((ext_vector_type(8)));
typedef __bf16 bf16x4 __attribute__((ext_vector_type(4)));
typedef short  s16x4  __attribute__((ext_vector_type(4)));
typedef float  f32x4  __attribute__((ext_vector_type(4)));
typedef unsigned int u32x4 __attribute__((ext_vector_type(4)));
typedef unsigned int u32x2 __attribute__((ext_vector_type(2)));

// prepped weight sizes (bf16 elements)
#define CHK_W_ELEMS 22272   // 24 x32-frags (512) + 39 x16-frags (256)
#define CHK_L2_OFF  12288
#define VAR_W_ELEMS 7168    // 7 x32-frags + 14 x16-frags
#define VAR_L2_OFF  3584

// Abramowitz-Stegun 7.1.26 erf (|eps| < 1.5e-7)
__device__ __forceinline__ float gelu_fast(float x) {
    float xe = x * 0.70710678118654752f;
    float ax = fabsf(xe);
    float t  = __builtin_amdgcn_rcpf(1.0f + 0.3275911f * ax);
    float p  = t * (0.254829592f + t * (-0.284496736f + t * (1.421413741f +
               t * (-1.453152027f + t * 1.061405429f))));
    float er = 1.0f - p * __expf(-xe * xe);
    er = copysignf(er, xe);
    return 0.5f * x * (1.0f + er);
}

// 16x16x16 bf16 MFMA: A[m=l&15][k=q*4+i], B[k=q*4+i][n=l&15],
// D[row=q*4+r][col=l&15]. B-layout == C/D-layout of a previous MFMA -> free
// layout chaining. Builtin preferred; asm fallback with hazard nops.
__device__ __forceinline__ f32x4 mfma16(bf16x4 a, bf16x4 b, f32x4 c) {
#if __has_builtin(__builtin_amdgcn_mfma_f32_16x16x16bf16_1k)
    return __builtin_amdgcn_mfma_f32_16x16x16bf16_1k(
        __builtin_bit_cast(s16x4, a), __builtin_bit_cast(s16x4, b), c, 0, 0, 0);
#else
    f32x4 d;
    asm volatile("v_mfma_f32_16x16x16_bf16 %0, %1, %2, %3\n\ts_nop 4"
                 : "=v"(d) : "v"(a), "v"(b), "v"(c));
    return d;
#endif
}

__device__ __forceinline__ unsigned pack2(float a, float b) {
    unsigned short ua = __builtin_bit_cast(unsigned short, (__bf16)a);
    unsigned short ub = __builtin_bit_cast(unsigned short, (__bf16)b);
    return (unsigned)ua | ((unsigned)ub << 16);
}

// ---------------------------------------------------------------------------
// init: v2c[e][b][0..7] = {bf16(prior[e/3]), 0,...}
// ---------------------------------------------------------------------------
__global__ __launch_bounds__(256)
void init_kernel(const float* __restrict__ prior, __bf16* __restrict__ v2c)
{
    int idx = blockIdx.x * 256 + threadIdx.x;
    int e = idx >> 7;
    bf16x8 v;
    #pragma unroll
    for (int j = 0; j < 8; ++j) v[j] = (__bf16)0.0f;
    v[0] = (__bf16)prior[e / 3];
    *(bf16x8*)(v2c + (size_t)idx * 8) = v;
}

// ---------------------------------------------------------------------------
// prep_all: fp32 -> bf16 W^T fragments in MFMA A-layout, biases folded:
//  chk L1 (x32): A[m=16mt+c][k=32kt+q*8+j] = W1^T[h][k]; k==48 -> b1[h]
//  chk L2 (x16): A[m=16mt+c][k=16ks+q*4+i] = W2^T[o][k]; ks==12 k==192 -> b2[o]
//  var L1 (x32): k<25 W1^T, k==25 -> b1, pads 0
//  var L2 (x16): k<100 W2^T, k==100 -> b2, pads 0
// Clamp-then-select keeps all gathers unconditional. One wave per task.
// ---------------------------------------------------------------------------
__global__ __launch_bounds__(256)
void prep_all(const float* __restrict__ cw1, const float* __restrict__ cb1,
              const float* __restrict__ cw2, const float* __restrict__ cb2,
              const float* __restrict__ vw1, const float* __restrict__ vb1,
              const float* __restrict__ vw2, const float* __restrict__ vb2,
              __bf16* __restrict__ wchk, __bf16* __restrict__ wvar)
{
    const int wid = blockIdx.x * 4 + (threadIdx.x >> 6);
    const int l = threadIdx.x & 63, q = l >> 4, c = l & 15;

    if (wid < 24576) {                                 // chk L1: (m, mt*2+kt)
        const int m = wid / 24, f = wid % 24;
        const int mt = f >> 1, kt = f & 1;
        const int h = mt * 16 + c;
        const float* s1 = cw1 + (size_t)m * (48 * 192);
        float tmp[8];
        #pragma unroll
        for (int j = 0; j < 8; ++j) {
            int k = kt * 32 + q * 8 + j;
            tmp[j] = s1[min(k, 47) * 192 + h];
        }
        float bv = cb1[(size_t)m * 192 + h];
        bf16x8 v;
        #pragma unroll
        for (int j = 0; j < 8; ++j) {
            int k = kt * 32 + q * 8 + j;
            float x = (k < 48) ? tmp[j] : ((k == 48) ? bv : 0.0f);
            v[j] = (__bf16)x;
        }
        *(bf16x8*)(wchk + (size_t)m * CHK_W_ELEMS + f * 512 + l * 8) = v;
    } else if (wid < 37888) {                          // chk L2: (m, ks), 3 mt
        const int t = wid - 24576;
        const int m = t / 13, ks = t % 13;
        __bf16* base = wchk + (size_t)m * CHK_W_ELEMS + CHK_L2_OFF;
        if (ks < 12) {
            const float* s2 = cw2 + (size_t)m * (192 * 48);
            #pragma unroll
            for (int mt = 0; mt < 3; ++mt) {
                const int o = mt * 16 + c;
                bf16x4 v;
                #pragma unroll
                for (int i = 0; i < 4; ++i)
                    v[i] = (__bf16)s2[(ks * 16 + q * 4 + i) * 48 + o];
                *(bf16x4*)(base + (ks * 3 + mt) * 256 + l * 4) = v;
            }
        } else {                                       // bias k-step
            #pragma unroll
            for (int mt = 0; mt < 3; ++mt) {
                const int o = mt * 16 + c;
                float bv = cb2[(size_t)m * 48 + o];
                bf16x4 v;
                #pragma unroll
                for (int i = 0; i < 4; ++i) v[i] = (__bf16)0.0f;
                if (q == 0) v[0] = (__bf16)bv;
                *(bf16x4*)(base + (12 * 3 + mt) * 256 + l * 4) = v;
            }
        }
    } else if (wid < 52224) {                          // var L1: (nv, mt)
        const int t = wid - 37888;
        const int nv = t / 7, mt = t % 7;
        const int h = mt * 16 + c, hc = min(h, 99);
        const float* s1 = vw1 + (size_t)nv * (25 * 100);
        float tmp[8];
        #pragma unroll
        for (int j = 0; j < 8; ++j)
            tmp[j] = s1[min(q * 8 + j, 24) * 100 + hc];
        float bv = vb1[(size_t)nv * 100 + hc];
        bf16x8 v;
        #pragma unroll
        for (int j = 0; j < 8; ++j) {
            int k = q * 8 + j;
            float x = 0.0f;
            if (h < 100) x = (k < 25) ? tmp[j] : ((k == 25) ? bv : 0.0f);
            v[j] = (__bf16)x;
        }
        *(bf16x8*)(wvar + (size_t)nv * VAR_W_ELEMS + mt * 512 + l * 8) = v;
    } else {                                           // var L2: (nv, ks), 2 mt
        const int t = wid - 52224;
        const int nv = t / 7, ks = t % 7;
        const float* s2 = vw2 + (size_t)nv * (100 * 25);
        __bf16* base = wvar + (size_t)nv * VAR_W_ELEMS + VAR_L2_OFF;
        #pragma unroll
        for (int mt = 0; mt < 2; ++mt) {
            const int o = mt * 16 + c, oc = min(o, 24);
            float tmp[4];
            #pragma unroll
            for (int i = 0; i < 4; ++i)
                tmp[i] = s2[min(ks * 16 + q * 4 + i, 99) * 25 + oc];
            float bv = vb2[(size_t)nv * 25 + oc];
            bf16x4 v;
            #pragma unroll
            for (int i = 0; i < 4; ++i) {
                int k = ks * 16 + q * 4 + i;
                float x = 0.0f;
                if (o < 25) x = (k < 100) ? tmp[i] : ((k == 100) ? bv : 0.0f);
                v[i] = (__bf16)x;
            }
            *(bf16x4*)(base + (ks * 2 + mt) * 256 + l * 4) = v;
        }
    }
}

// ---------------------------------------------------------------------------
// Check MLP, fully transposed: D1[h][b] = W1^T·X^T (x32), GELU in regs,
// D2[o][b] = W2^T·H^T (x16, B-frag IS the gelu'd acc registers).
// No LDS scratch, no fences; one barrier after weight staging.
// ---------------------------------------------------------------------------
__global__ __launch_bounds__(256, 3)
void chk_kernel(const __bf16* __restrict__ wchk,
                const int* __restrict__ syndromes,
                const int* __restrict__ v2c_gather,
                const __bf16* __restrict__ v2c, __bf16* __restrict__ c2v)
{
    const int m = blockIdx.x;
    const int tid = threadIdx.x;
    const int w = tid >> 6, l = tid & 63, q = l >> 4, c = l & 15;

    __shared__ __align__(16) __bf16 wlds[CHK_W_ELEMS];   // 43.5 KB
    {
        const __bf16* src = wchk + (size_t)m * CHK_W_ELEMS;
        for (int i = tid; i < CHK_W_ELEMS / 8; i += 256)
            *(u32x4*)(wlds + i * 8) = *(const u32x4*)(src + i * 8);
    }
    const int e0 = v2c_gather[m * 6 + q];                   // slot q
    const int e1 = (q < 2) ? v2c_gather[m * 6 + 4 + q] : 0; // slots 4,5
    __syncthreads();

    for (int t2 = 0; t2 < 2; ++t2) {
        const int bt = t2 * 64 + w * 16;

        // X^T B-frags: lane (q,c) holds message[slot][batch bt+c][d=j]
        bf16x8 b0 = *(const bf16x8*)(v2c + ((size_t)e0 * BB + bt + c) * 8);
        bf16x8 b1f;
        #pragma unroll
        for (int j = 0; j < 8; ++j) b1f[j] = (__bf16)0.0f;
        if (q < 2)       b1f = *(const bf16x8*)(v2c + ((size_t)e1 * BB + bt + c) * 8);
        else if (q == 2) b1f[0] = (__bf16)1.0f;   // bias row k=48

        // layer 1: 12 hidden tiles, acc[mt] row=q*4+r (hidden), col=c (batch)
        f32x4 acc[12];
        #pragma unroll
        for (int mt = 0; mt < 12; ++mt) {
            bf16x8 a0 = *(const bf16x8*)(wlds + (mt * 2 + 0) * 512 + l * 8);
            bf16x8 a1 = *(const bf16x8*)(wlds + (mt * 2 + 1) * 512 + l * 8);
            f32x4 z = {0.f, 0.f, 0.f, 0.f};
            z = __builtin_amdgcn_mfma_f32_16x16x32_bf16(a0, b0, z, 0, 0, 0);
            z = __builtin_amdgcn_mfma_f32_16x16x32_bf16(a1, b1f, z, 0, 0, 0);
            acc[mt] = z;
        }

        // layer 2: 13 x16 k-steps (ks=12 = b2 bias step), B-frag = gelu(acc)
        f32x4 acc2[3];
        #pragma unroll
        for (int mt = 0; mt < 3; ++mt) acc2[mt] = (f32x4){0.f, 0.f, 0.f, 0.f};
        #pragma unroll
        for (int ks = 0; ks < 13; ++ks) {
            bf16x4 bf;
            if (ks < 12) {
                #pragma unroll
                for (int r = 0; r < 4; ++r) bf[r] = (__bf16)gelu_fast(acc[ks][r]);
            } else {
                #pragma unroll
                for (int r = 0; r < 4; ++r) bf[r] = (__bf16)0.0f;
                if (q == 0) bf[0] = (__bf16)1.0f;   // k=192 bias row
            }
            #pragma unroll
            for (int mt = 0; mt < 3; ++mt) {
                bf16x4 af = *(const bf16x4*)(wlds + CHK_L2_OFF + (ks * 3 + mt) * 256 + l * 4);
                acc2[mt] = mfma16(af, bf, acc2[mt]);
            }
        }

        // epilogue: Y^T row=out(16mt+q*4+r), col=batch(c); sign per batch col
        const float sg = (float)(1 - 2 * syndromes[(size_t)(bt + c) * MM + m]);
        #pragma unroll
        for (int mt = 0; mt < 3; ++mt) {
            u32x2 pv = { pack2(acc2[mt][0] * sg, acc2[mt][1] * sg),
                         pack2(acc2[mt][2] * sg, acc2[mt][3] * sg) };
            int s = 2 * mt + (q >> 1);                   // d = (q&1)*4 + r
            *(u32x2*)(c2v + ((size_t)(m * 6 + s) * BB + bt + c) * 8 + (q & 1) * 4) = pv;
        }
    }
}

// ---------------------------------------------------------------------------
// Variable MLP, same transposed structure. LLR = out-row 24 (mt=1,q=2,r=0).
// ---------------------------------------------------------------------------
__global__ __launch_bounds__(256, 4)
void var_kernel(const __bf16* __restrict__ wvar,
                const int* __restrict__ c2v_gather, const float* __restrict__ prior,
                const __bf16* __restrict__ c2v, __bf16* __restrict__ v2c,
                float* __restrict__ llr_out, int last)
{
    const int nv = blockIdx.x;
    const int tid = threadIdx.x;
    const int w = tid >> 6, l = tid & 63, q = l >> 4, c = l & 15;

    __shared__ __align__(16) __bf16 wlds[VAR_W_ELEMS];   // 14.3 KB
    {
        const __bf16* src = wvar + (size_t)nv * VAR_W_ELEMS;
        for (int i = tid; i < VAR_W_ELEMS / 8; i += 256)
            *(u32x4*)(wlds + i * 8) = *(const u32x4*)(src + i * 8);
    }
    const int ep = (q < 3) ? c2v_gather[nv * 3 + q] : 0;
    const __bf16 prbf = (__bf16)prior[nv];
    __syncthreads();

    for (int t2 = 0; t2 < 2; ++t2) {
        const int bt = t2 * 64 + w * 16;

        bf16x8 b0;
        #pragma unroll
        for (int j = 0; j < 8; ++j) b0[j] = (__bf16)0.0f;
        if (q < 3) b0 = *(const bf16x8*)(c2v + ((size_t)ep * BB + bt + c) * 8);
        else { b0[0] = prbf; b0[1] = (__bf16)1.0f; }   // k=24 prior, k=25 bias

        f32x4 acc[7];
        #pragma unroll
        for (int mt = 0; mt < 7; ++mt) {
            bf16x8 a0 = *(const bf16x8*)(wlds + mt * 512 + l * 8);
            f32x4 z = {0.f, 0.f, 0.f, 0.f};
            acc[mt] = __builtin_amdgcn_mfma_f32_16x16x32_bf16(a0, b0, z, 0, 0, 0);
        }

        f32x4 acc2[2];
        acc2[0] = (f32x4){0.f, 0.f, 0.f, 0.f};
        acc2[1] = (f32x4){0.f, 0.f, 0.f, 0.f};
        #pragma unroll
        for (int ks = 0; ks < 7; ++ks) {
            bf16x4 bf;
            #pragma unroll
            for (int r = 0; r < 4; ++r) bf[r] = (__bf16)gelu_fast(acc[ks][r]);
            if (ks == 6 && q == 1) bf[0] = (__bf16)1.0f;   // k=100 bias row
            #pragma unroll
            for (int mt = 0; mt < 2; ++mt) {
                bf16x4 af = *(const bf16x4*)(wlds + VAR_L2_OFF + (ks * 2 + mt) * 256 + l * 4);
                acc2[mt] = mfma16(af, bf, acc2[mt]);
            }
        }

        // epilogue: out = 16mt + q*4 + r, col=batch c
        if (!last) {
            u32x2 p0 = { pack2(acc2[0][0], acc2[0][1]), pack2(acc2[0][2], acc2[0][3]) };
            int s0 = q >> 1;
            *(u32x2*)(v2c + ((size_t)(nv * 3 + s0) * BB + bt + c) * 8 + (q & 1) * 4) = p0;
            if (q < 2) {
                u32x2 p1 = { pack2(acc2[1][0], acc2[1][1]), pack2(acc2[1][2], acc2[1][3]) };
                *(u32x2*)(v2c + ((size_t)(nv * 3 + 2) * BB + bt + c) * 8 + (q & 1) * 4) = p1;
            }
        }
        if (q == 2) llr_out[(size_t)(bt + c) * NN + nv] = acc2[1][0];   // out=24
    }
}

extern "C" void kernel_launch(void* const* d_in, const int* in_sizes, int n_in,
                              void* d_out, int out_size, void* d_ws, size_t ws_size,
                              hipStream_t stream) {
    const int*   syndromes = (const int*)  d_in[0];
    const float* prior_llr = (const float*)d_in[1];
    const float* chk_w1    = (const float*)d_in[2];
    const float* chk_b1    = (const float*)d_in[3];
    const float* chk_w2    = (const float*)d_in[4];
    const float* chk_b2    = (const float*)d_in[5];
    const float* var_w1    = (const float*)d_in[6];
    const float* var_b1    = (const float*)d_in[7];
    const float* var_w2    = (const float*)d_in[8];
    const float* var_b2    = (const float*)d_in[9];
    const int*   c2v_g     = (const int*)  d_in[11];
    const int*   v2c_g     = (const int*)  d_in[12];

    float* out = (float*)d_out;

    __bf16* v2c  = (__bf16*)d_ws;                           // 12.6 MB
    __bf16* c2v  = v2c + (size_t)EE * BB * 8;               // 12.6 MB
    __bf16* wchk = c2v + (size_t)EE * BB * 8;               // 45.6 MB
    __bf16* wvar = wchk + (size_t)MM * CHK_W_ELEMS;         // 29.4 MB

    // waves: chk L1 24576 | chk L2 13312 | var L1 14336 | var L2 14336 = 66560
    prep_all<<<16640, 256, 0, stream>>>(chk_w1, chk_b1, chk_w2, chk_b2,
                                        var_w1, var_b1, var_w2, var_b2,
                                        wchk, wvar);
    init_kernel<<<EE * BB / 256, 256, 0, stream>>>(prior_llr, v2c);

    for (int t = 0; t < TT; ++t) {
        chk_kernel<<<MM, 256, 0, stream>>>(wchk, syndromes, v2c_g, v2c, c2v);
        var_kernel<<<NN, 256, 0, stream>>>(wvar, c2v_g, prior_llr, c2v, v2c,
                                           out + (size_t)t * BB * NN,
                                           (t == TT - 1) ? 1 : 0);
    }
}

// Round 9
// 402.813 us; speedup vs baseline: 1.4037x; 1.4037x over previous
//
#include <hip/hip_runtime.h>
#include <math.h>

#define MM 1024      // checks
#define NN 2048      // vars
#define BB 128       // batch
#define TT 5         // iterations
#define EE 6144      // edges

typedef __bf16 bf16x8 __attribute__((ext_vector_type(8)));
typedef __bf16 bf16x4 __attribute__((ext_vector_type(4)));
typedef short  s16x4  __attribute__((ext_vector_type(4)));
typedef float  f32x4  __attribute__((ext_vector_type(4)));
typedef unsigned int u32x4 __attribute__((ext_vector_type(4)));

// prepped weight sizes (bf16 elements)
#define CHK_W_ELEMS 22272   // 24 x32-frags (512) + 39 x16-frags (256)
#define CHK_L2_OFF  12288
#define VAR_W_ELEMS 7168    // 7 x32-frags + 14 x16-frags
#define VAR_L2_OFF  3584

// Abramowitz-Stegun 7.1.26 erf (|eps| < 1.5e-7)
__device__ __forceinline__ float gelu_fast(float x) {
    float xe = x * 0.70710678118654752f;
    float ax = fabsf(xe);
    float t  = __builtin_amdgcn_rcpf(1.0f + 0.3275911f * ax);
    float p  = t * (0.254829592f + t * (-0.284496736f + t * (1.421413741f +
               t * (-1.453152027f + t * 1.061405429f))));
    float er = 1.0f - p * __expf(-xe * xe);
    er = copysignf(er, xe);
    return 0.5f * x * (1.0f + er);
}

// 16x16x16 bf16 MFMA: B-operand layout == C/D layout of a prior MFMA ->
// register-chained layer2 (no LDS transpose on the critical path).
__device__ __forceinline__ f32x4 mfma16(bf16x4 a, bf16x4 b, f32x4 c) {
#if __has_builtin(__builtin_amdgcn_mfma_f32_16x16x16bf16_1k)
    return __builtin_amdgcn_mfma_f32_16x16x16bf16_1k(
        __builtin_bit_cast(s16x4, a), __builtin_bit_cast(s16x4, b), c, 0, 0, 0);
#else
    f32x4 d;
    asm volatile("v_mfma_f32_16x16x16_bf16 %0, %1, %2, %3\n\ts_nop 4"
                 : "=v"(d) : "v"(a), "v"(b), "v"(c));
    return d;
#endif
}

// wave-private LDS fence (DS ops in-order per wave)
__device__ __forceinline__ void wave_lds_fence() {
    asm volatile("s_waitcnt lgkmcnt(0)" ::: "memory");
}

__global__ __launch_bounds__(256)
void init_kernel(const float* __restrict__ prior, __bf16* __restrict__ v2c)
{
    int idx = blockIdx.x * 256 + threadIdx.x;
    int e = idx >> 7;
    bf16x8 v;
    #pragma unroll
    for (int j = 0; j < 8; ++j) v[j] = (__bf16)0.0f;
    v[0] = (__bf16)prior[e / 3];
    *(bf16x8*)(v2c + (size_t)idx * 8) = v;
}

// syndrome signs transposed: sgnT[m][b] (coalesced f32 reads in chk)
__global__ __launch_bounds__(256)
void sgn_kernel(const int* __restrict__ synd, float* __restrict__ sgnT)
{
    int idx = blockIdx.x * 256 + threadIdx.x;    // m*128 + b
    int m = idx >> 7, b = idx & 127;
    sgnT[idx] = (float)(1 - 2 * synd[(size_t)b * MM + m]);
}

// ---------------------------------------------------------------------------
// prep_all: fp32 -> bf16 W^T fragments in MFMA A-layout, biases folded.
// Clamp-then-select keeps all gathers unconditional. One wave per task.
// ---------------------------------------------------------------------------
__global__ __launch_bounds__(256)
void prep_all(const float* __restrict__ cw1, const float* __restrict__ cb1,
              const float* __restrict__ cw2, const float* __restrict__ cb2,
              const float* __restrict__ vw1, const float* __restrict__ vb1,
              const float* __restrict__ vw2, const float* __restrict__ vb2,
              __bf16* __restrict__ wchk, __bf16* __restrict__ wvar)
{
    const int wid = blockIdx.x * 4 + (threadIdx.x >> 6);
    const int l = threadIdx.x & 63, q = l >> 4, c = l & 15;

    if (wid < 24576) {                                 // chk L1: (m, mt*2+kt)
        const int m = wid / 24, f = wid % 24;
        const int mt = f >> 1, kt = f & 1;
        const int h = mt * 16 + c;
        const float* s1 = cw1 + (size_t)m * (48 * 192);
        float tmp[8];
        #pragma unroll
        for (int j = 0; j < 8; ++j) {
            int k = kt * 32 + q * 8 + j;
            tmp[j] = s1[min(k, 47) * 192 + h];
        }
        float bv = cb1[(size_t)m * 192 + h];
        bf16x8 v;
        #pragma unroll
        for (int j = 0; j < 8; ++j) {
            int k = kt * 32 + q * 8 + j;
            float x = (k < 48) ? tmp[j] : ((k == 48) ? bv : 0.0f);
            v[j] = (__bf16)x;
        }
        *(bf16x8*)(wchk + (size_t)m * CHK_W_ELEMS + f * 512 + l * 8) = v;
    } else if (wid < 37888) {                          // chk L2: (m, ks), 3 mt
        const int t = wid - 24576;
        const int m = t / 13, ks = t % 13;
        __bf16* base = wchk + (size_t)m * CHK_W_ELEMS + CHK_L2_OFF;
        if (ks < 12) {
            const float* s2 = cw2 + (size_t)m * (192 * 48);
            #pragma unroll
            for (int mt = 0; mt < 3; ++mt) {
                const int o = mt * 16 + c;
                bf16x4 v;
                #pragma unroll
                for (int i = 0; i < 4; ++i)
                    v[i] = (__bf16)s2[(ks * 16 + q * 4 + i) * 48 + o];
                *(bf16x4*)(base + (ks * 3 + mt) * 256 + l * 4) = v;
            }
        } else {
            #pragma unroll
            for (int mt = 0; mt < 3; ++mt) {
                const int o = mt * 16 + c;
                float bv = cb2[(size_t)m * 48 + o];
                bf16x4 v;
                #pragma unroll
                for (int i = 0; i < 4; ++i) v[i] = (__bf16)0.0f;
                if (q == 0) v[0] = (__bf16)bv;
                *(bf16x4*)(base + (12 * 3 + mt) * 256 + l * 4) = v;
            }
        }
    } else if (wid < 52224) {                          // var L1: (nv, mt)
        const int t = wid - 37888;
        const int nv = t / 7, mt = t % 7;
        const int h = mt * 16 + c, hc = min(h, 99);
        const float* s1 = vw1 + (size_t)nv * (25 * 100);
        float tmp[8];
        #pragma unroll
        for (int j = 0; j < 8; ++j)
            tmp[j] = s1[min(q * 8 + j, 24) * 100 + hc];
        float bv = vb1[(size_t)nv * 100 + hc];
        bf16x8 v;
        #pragma unroll
        for (int j = 0; j < 8; ++j) {
            int k = q * 8 + j;
            float x = 0.0f;
            if (h < 100) x = (k < 25) ? tmp[j] : ((k == 25) ? bv : 0.0f);
            v[j] = (__bf16)x;
        }
        *(bf16x8*)(wvar + (size_t)nv * VAR_W_ELEMS + mt * 512 + l * 8) = v;
    } else {                                           // var L2: (nv, ks), 2 mt
        const int t = wid - 52224;
        const int nv = t / 7, ks = t % 7;
        const float* s2 = vw2 + (size_t)nv * (100 * 25);
        __bf16* base = wvar + (size_t)nv * VAR_W_ELEMS + VAR_L2_OFF;
        #pragma unroll
        for (int mt = 0; mt < 2; ++mt) {
            const int o = mt * 16 + c, oc = min(o, 24);
            float tmp[4];
            #pragma unroll
            for (int i = 0; i < 4; ++i)
                tmp[i] = s2[min(ks * 16 + q * 4 + i, 99) * 25 + oc];
            float bv = vb2[(size_t)nv * 25 + oc];
            bf16x4 v;
            #pragma unroll
            for (int i = 0; i < 4; ++i) {
                int k = ks * 16 + q * 4 + i;
                float x = 0.0f;
                if (o < 25) x = (k < 100) ? tmp[i] : ((k == 100) ? bv : 0.0f);
                v[i] = (__bf16)x;
            }
            *(bf16x4*)(base + (ks * 2 + mt) * 256 + l * 4) = v;
        }
    }
}

// ---------------------------------------------------------------------------
// Check MLP, transposed register-chained compute (r8) + LDS-tile epilogue
// with 16B-chunk coalesced stores (r7's proven path).
// ---------------------------------------------------------------------------
#define CPITCH 58   // Y tile pitch (elements); 29c mod 32 spreads banks
__global__ __launch_bounds__(256, 3)
void chk_kernel(const __bf16* __restrict__ wchk,
                const float* __restrict__ sgnT,
                const int* __restrict__ v2c_gather,
                const __bf16* __restrict__ v2c, __bf16* __restrict__ c2v)
{
    const int m = blockIdx.x;
    const int tid = threadIdx.x;
    const int w = tid >> 6, l = tid & 63, q = l >> 4, c = l & 15;

    __shared__ __align__(16) __bf16 wlds[CHK_W_ELEMS];      // 43.5 KB
    __shared__ __align__(16) __bf16 ytile[4 * 16 * CPITCH]; // 7.25 KB
    {
        const __bf16* src = wchk + (size_t)m * CHK_W_ELEMS;
        for (int i = tid; i < CHK_W_ELEMS / 8; i += 256)
            *(u32x4*)(wlds + i * 8) = *(const u32x4*)(src + i * 8);
    }
    const int e0 = v2c_gather[m * 6 + q];
    const int e1 = (q < 2) ? v2c_gather[m * 6 + 4 + q] : 0;
    __syncthreads();

    __bf16* myy = ytile + w * 16 * CPITCH;   // [batch 16][out 48], wave-private

    for (int t2 = 0; t2 < 2; ++t2) {
        const int bt = t2 * 64 + w * 16;

        // X^T B-frags
        bf16x8 b0 = *(const bf16x8*)(v2c + ((size_t)e0 * BB + bt + c) * 8);
        bf16x8 b1f;
        #pragma unroll
        for (int j = 0; j < 8; ++j) b1f[j] = (__bf16)0.0f;
        if (q < 2)       b1f = *(const bf16x8*)(v2c + ((size_t)e1 * BB + bt + c) * 8);
        else if (q == 2) b1f[0] = (__bf16)1.0f;   // bias row k=48

        // layer 1: 12 hidden tiles (x32)
        f32x4 acc[12];
        #pragma unroll
        for (int mt = 0; mt < 12; ++mt) {
            bf16x8 a0 = *(const bf16x8*)(wlds + (mt * 2 + 0) * 512 + l * 8);
            bf16x8 a1 = *(const bf16x8*)(wlds + (mt * 2 + 1) * 512 + l * 8);
            f32x4 z = {0.f, 0.f, 0.f, 0.f};
            z = __builtin_amdgcn_mfma_f32_16x16x32_bf16(a0, b0, z, 0, 0, 0);
            z = __builtin_amdgcn_mfma_f32_16x16x32_bf16(a1, b1f, z, 0, 0, 0);
            acc[mt] = z;
        }

        // layer 2: 13 x16 k-steps, B-frag = gelu(acc) straight from registers
        f32x4 acc2[3];
        #pragma unroll
        for (int mt = 0; mt < 3; ++mt) acc2[mt] = (f32x4){0.f, 0.f, 0.f, 0.f};
        #pragma unroll
        for (int ks = 0; ks < 13; ++ks) {
            bf16x4 bf;
            if (ks < 12) {
                #pragma unroll
                for (int r = 0; r < 4; ++r) bf[r] = (__bf16)gelu_fast(acc[ks][r]);
            } else {
                #pragma unroll
                for (int r = 0; r < 4; ++r) bf[r] = (__bf16)0.0f;
                if (q == 0) bf[0] = (__bf16)1.0f;   // k=192 bias row
            }
            #pragma unroll
            for (int mt = 0; mt < 3; ++mt) {
                bf16x4 af = *(const bf16x4*)(wlds + CHK_L2_OFF + (ks * 3 + mt) * 256 + l * 4);
                acc2[mt] = mfma16(af, bf, acc2[mt]);
            }
        }

        // epilogue: sign + transpose via wave-private LDS tile [b][o]
        const float sg = sgnT[m * BB + bt + c];
        #pragma unroll
        for (int mt = 0; mt < 3; ++mt)
            #pragma unroll
            for (int r = 0; r < 4; ++r)
                myy[c * CPITCH + mt * 16 + q * 4 + r] = (__bf16)(acc2[mt][r] * sg);
        wave_lds_fence();

        // coalesced 16B chunk stores: (slot s, row) -> c2v[e=m*6+s][bt+row][0..7]
        {
            int s = l >> 4, row = l & 15;
            u32x4 vv = *(const u32x4*)(myy + row * CPITCH + s * 8);
            *(u32x4*)(c2v + ((size_t)(m * 6 + s) * BB + bt + row) * 8) = vv;
            if (l < 32) {
                int s2 = 4 + (l >> 4), row2 = l & 15;
                u32x4 v2 = *(const u32x4*)(myy + row2 * CPITCH + s2 * 8);
                *(u32x4*)(c2v + ((size_t)(m * 6 + s2) * BB + bt + row2) * 8) = v2;
            }
        }
        wave_lds_fence();   // reads done before next-t2 tile writes
    }
}

// ---------------------------------------------------------------------------
// Variable MLP, same structure. LLR (out=24) stored f32 from register.
// ---------------------------------------------------------------------------
#define VPITCH 26
__global__ __launch_bounds__(256, 4)
void var_kernel(const __bf16* __restrict__ wvar,
                const int* __restrict__ c2v_gather, const float* __restrict__ prior,
                const __bf16* __restrict__ c2v, __bf16* __restrict__ v2c,
                float* __restrict__ llr_out, int last)
{
    const int nv = blockIdx.x;
    const int tid = threadIdx.x;
    const int w = tid >> 6, l = tid & 63, q = l >> 4, c = l & 15;

    __shared__ __align__(16) __bf16 wlds[VAR_W_ELEMS];      // 14.3 KB
    __shared__ __align__(16) __bf16 ytile[4 * 16 * VPITCH]; // 3.25 KB
    {
        const __bf16* src = wvar + (size_t)nv * VAR_W_ELEMS;
        for (int i = tid; i < VAR_W_ELEMS / 8; i += 256)
            *(u32x4*)(wlds + i * 8) = *(const u32x4*)(src + i * 8);
    }
    const int ep = (q < 3) ? c2v_gather[nv * 3 + q] : 0;
    const __bf16 prbf = (__bf16)prior[nv];
    __syncthreads();

    __bf16* myy = ytile + w * 16 * VPITCH;   // [batch 16][out 24]

    for (int t2 = 0; t2 < 2; ++t2) {
        const int bt = t2 * 64 + w * 16;

        bf16x8 b0;
        #pragma unroll
        for (int j = 0; j < 8; ++j) b0[j] = (__bf16)0.0f;
        if (q < 3) b0 = *(const bf16x8*)(c2v + ((size_t)ep * BB + bt + c) * 8);
        else { b0[0] = prbf; b0[1] = (__bf16)1.0f; }   // k=24 prior, k=25 bias

        f32x4 acc[7];
        #pragma unroll
        for (int mt = 0; mt < 7; ++mt) {
            bf16x8 a0 = *(const bf16x8*)(wlds + mt * 512 + l * 8);
            f32x4 z = {0.f, 0.f, 0.f, 0.f};
            acc[mt] = __builtin_amdgcn_mfma_f32_16x16x32_bf16(a0, b0, z, 0, 0, 0);
        }

        f32x4 acc2[2];
        acc2[0] = (f32x4){0.f, 0.f, 0.f, 0.f};
        acc2[1] = (f32x4){0.f, 0.f, 0.f, 0.f};
        #pragma unroll
        for (int ks = 0; ks < 7; ++ks) {
            bf16x4 bf;
            #pragma unroll
            for (int r = 0; r < 4; ++r) bf[r] = (__bf16)gelu_fast(acc[ks][r]);
            if (ks == 6 && q == 1) bf[0] = (__bf16)1.0f;   // k=100 bias row
            #pragma unroll
            for (int mt = 0; mt < 2; ++mt) {
                bf16x4 af = *(const bf16x4*)(wlds + VAR_L2_OFF + (ks * 2 + mt) * 256 + l * 4);
                acc2[mt] = mfma16(af, bf, acc2[mt]);
            }
        }

        // epilogue: messages (o<24) via LDS tile; LLR (o=24) f32 direct
        #pragma unroll
        for (int r = 0; r < 4; ++r)
            myy[c * VPITCH + q * 4 + r] = (__bf16)acc2[0][r];
        if (q < 2)
            #pragma unroll
            for (int r = 0; r < 4; ++r)
                myy[c * VPITCH + 16 + q * 4 + r] = (__bf16)acc2[1][r];
        if (q == 2) llr_out[(size_t)(bt + c) * NN + nv] = acc2[1][0];
        wave_lds_fence();

        if (!last && l < 48) {
            int s = l >> 4, row = l & 15;
            u32x4 vv = *(const u32x4*)(myy + row * VPITCH + s * 8);
            *(u32x4*)(v2c + ((size_t)(nv * 3 + s) * BB + bt + row) * 8) = vv;
        }
        wave_lds_fence();
    }
}

extern "C" void kernel_launch(void* const* d_in, const int* in_sizes, int n_in,
                              void* d_out, int out_size, void* d_ws, size_t ws_size,
                              hipStream_t stream) {
    const int*   syndromes = (const int*)  d_in[0];
    const float* prior_llr = (const float*)d_in[1];
    const float* chk_w1    = (const float*)d_in[2];
    const float* chk_b1    = (const float*)d_in[3];
    const float* chk_w2    = (const float*)d_in[4];
    const float* chk_b2    = (const float*)d_in[5];
    const float* var_w1    = (const float*)d_in[6];
    const float* var_b1    = (const float*)d_in[7];
    const float* var_w2    = (const float*)d_in[8];
    const float* var_b2    = (const float*)d_in[9];
    const int*   c2v_g     = (const int*)  d_in[11];
    const int*   v2c_g     = (const int*)  d_in[12];

    float* out = (float*)d_out;

    __bf16* v2c  = (__bf16*)d_ws;                           // 12.6 MB
    __bf16* c2v  = v2c + (size_t)EE * BB * 8;               // 12.6 MB
    __bf16* wchk = c2v + (size_t)EE * BB * 8;               // 45.6 MB
    __bf16* wvar = wchk + (size_t)MM * CHK_W_ELEMS;         // 29.4 MB
    float*  sgnT = (float*)(wvar + (size_t)NN * VAR_W_ELEMS); // 512 KB

    prep_all<<<16640, 256, 0, stream>>>(chk_w1, chk_b1, chk_w2, chk_b2,
                                        var_w1, var_b1, var_w2, var_b2,
                                        wchk, wvar);
    sgn_kernel<<<MM * BB / 256, 256, 0, stream>>>(syndromes, sgnT);
    init_kernel<<<EE * BB / 256, 256, 0, stream>>>(prior_llr, v2c);

    for (int t = 0; t < TT; ++t) {
        chk_kernel<<<MM, 256, 0, stream>>>(wchk, sgnT, v2c_g, v2c, c2v);
        var_kernel<<<NN, 256, 0, stream>>>(wvar, c2v_g, prior_llr, c2v, v2c,
                                           out + (size_t)t * BB * NN,
                                           (t == TT - 1) ? 1 : 0);
    }
}